// Round 1
// baseline (569.731 us; speedup 1.0000x reference)
//
#include <hip/hip_runtime.h>
#include <hip/hip_bf16.h>

// ---------------- problem dims (fixed) ----------------
#define BB 2
#define LL 2048
#define EE 1024
#define NHH 16
#define DHH 64
#define HIDD 4096
#define MTOK (BB*LL)          // 4096 tokens
#define NQKV (NHH*3*DHH)      // 3072

typedef __attribute__((ext_vector_type(8))) short bf16x8;   // 8 bf16 in 4 VGPRs
typedef __attribute__((ext_vector_type(4))) float f32x4;

#define MFMA16(a,b,c) __builtin_amdgcn_mfma_f32_16x16x32_bf16(a,b,c,0,0,0)

static __device__ __forceinline__ void gload_lds16(const void* g, void* lds) {
  __builtin_amdgcn_global_load_lds(
      (const __attribute__((address_space(1))) unsigned int*)g,
      (__attribute__((address_space(3))) unsigned int*)lds, 16, 0, 0);
}

// ---------------- weight fp32 -> bf16 transpose-convert ----------------
// W: K x N row-major f32  ->  WT: N x K row-major bf16
__global__ __launch_bounds__(256)
void convT_kernel(const float* __restrict__ W, __hip_bfloat16* __restrict__ WT,
                  int K, int N) {
  __shared__ float tile[32][33];
  const int tx = threadIdx.x & 31, ty = threadIdx.x >> 5;   // ty 0..7
  const int n0 = blockIdx.x * 32, k0 = blockIdx.y * 32;
#pragma unroll
  for (int i = 0; i < 4; ++i)
    tile[ty + i*8][tx] = W[(size_t)(k0 + ty + i*8) * N + n0 + tx];
  __syncthreads();
#pragma unroll
  for (int i = 0; i < 4; ++i)
    WT[(size_t)(n0 + ty + i*8) * K + k0 + tx] = __float2bfloat16(tile[tx][ty + i*8]);
}

// ---------------- LayerNorm (fp32 in, bf16 out), row = 1024 ----------------
__global__ __launch_bounds__(256)
void ln_kernel(const float* __restrict__ in, const float* __restrict__ g,
               const float* __restrict__ be, __hip_bfloat16* __restrict__ out) {
  const int row = blockIdx.x;
  const int t = threadIdx.x;
  const float4 v = ((const float4*)(in + (size_t)row * EE))[t];
  float s = v.x + v.y + v.z + v.w;
  float q = v.x*v.x + v.y*v.y + v.z*v.z + v.w*v.w;
#pragma unroll
  for (int off = 32; off >= 1; off >>= 1) {
    s += __shfl_xor(s, off);
    q += __shfl_xor(q, off);
  }
  __shared__ float ps[4], pq[4];
  if ((t & 63) == 0) { ps[t >> 6] = s; pq[t >> 6] = q; }
  __syncthreads();
  s = ps[0] + ps[1] + ps[2] + ps[3];
  q = pq[0] + pq[1] + pq[2] + pq[3];
  const float mean = s * (1.0f / EE);
  const float rstd = rsqrtf(q * (1.0f / EE) - mean * mean + 1e-5f);
  const float4 gg = ((const float4*)g)[t];
  const float4 bb = ((const float4*)be)[t];
  union { ushort4 u; __hip_bfloat16 h[4]; } o;
  o.h[0] = __float2bfloat16((v.x - mean) * rstd * gg.x + bb.x);
  o.h[1] = __float2bfloat16((v.y - mean) * rstd * gg.y + bb.y);
  o.h[2] = __float2bfloat16((v.z - mean) * rstd * gg.z + bb.z);
  o.h[3] = __float2bfloat16((v.w - mean) * rstd * gg.w + bb.w);
  ((ushort4*)(out + (size_t)row * EE))[t] = o.u;
}

// ---------------- bf16 MFMA GEMM: C = A(MxK) * BT(NxK)^T ----------------
// 128x128 tile, BK=32, 256 threads (4 waves, 2x2 of 64x64), m97 structure.
template<int OUT_BF16, int HAS_BIAS, int HAS_RES>
__global__ __launch_bounds__(256)
void gemm_kernel(const __hip_bfloat16* __restrict__ A,
                 const __hip_bfloat16* __restrict__ BT,
                 void* __restrict__ Cv,
                 const float* __restrict__ bias,
                 const float* __restrict__ res,
                 int M, int N, int K) {
  __shared__ alignas(16) __hip_bfloat16 sA[128 * 32];
  __shared__ alignas(16) __hip_bfloat16 sB[128 * 32];
  const int t = threadIdx.x;
  const int wv = t >> 6;
  const int l = t & 63;
  const int lr = l & 15;            // row/col within a 16-group
  const int lk = (l >> 4) * 8;      // k octet
  const int m0 = blockIdx.y * 128;
  const int n0 = blockIdx.x * 128;
  const int wrow = (wv >> 1) * 64;
  const int wcol = (wv & 1) * 64;

  // staging: thread t covers LDS bytes [t*16, t*16+16) => row t>>2, col (t&3)*8
  const int srow = t >> 2;
  const int scol = (t & 3) * 8;
  const __hip_bfloat16* gA = A + (size_t)(m0 + srow) * K + scol;
  const __hip_bfloat16* gB = BT + (size_t)(n0 + srow) * K + scol;
  char* ldsA = (char*)sA + wv * 1024;
  char* ldsB = (char*)sB + wv * 1024;

  f32x4 acc[4][4] = {};

  for (int k0 = 0; k0 < K; k0 += 32) {
    gload_lds16(gA + k0, ldsA);
    gload_lds16(gA + (size_t)64 * K + k0, ldsA + 4096);
    gload_lds16(gB + k0, ldsB);
    gload_lds16(gB + (size_t)64 * K + k0, ldsB + 4096);
    __syncthreads();
    bf16x8 af[4], bfv[4];
#pragma unroll
    for (int mi = 0; mi < 4; ++mi)
      af[mi] = *(const bf16x8*)(sA + (wrow + mi * 16 + lr) * 32 + lk);
#pragma unroll
    for (int ni = 0; ni < 4; ++ni)
      bfv[ni] = *(const bf16x8*)(sB + (wcol + ni * 16 + lr) * 32 + lk);
#pragma unroll
    for (int mi = 0; mi < 4; ++mi)
#pragma unroll
      for (int ni = 0; ni < 4; ++ni)
        acc[mi][ni] = MFMA16(af[mi], bfv[ni], acc[mi][ni]);
    __syncthreads();
  }

  const int rbase = (l >> 4) * 4;
#pragma unroll
  for (int mi = 0; mi < 4; ++mi) {
#pragma unroll
    for (int ni = 0; ni < 4; ++ni) {
#pragma unroll
      for (int r = 0; r < 4; ++r) {
        const int row = m0 + wrow + mi * 16 + rbase + r;
        const int col = n0 + wcol + ni * 16 + lr;
        float v = acc[mi][ni][r];
        if constexpr (HAS_BIAS) v += bias[col];
        if constexpr (HAS_RES)  v += res[(size_t)row * N + col];
        if constexpr (OUT_BF16)
          ((__hip_bfloat16*)Cv)[(size_t)row * N + col] = __float2bfloat16(v);
        else
          ((float*)Cv)[(size_t)row * N + col] = v;
      }
    }
  }
}

// ---------------- causal flash attention ----------------
// grid (L/64, NH, B), 256 threads. 4 waves x 16 q-rows, KV tiles of 32.
__global__ __launch_bounds__(256)
void attn_kernel(const __hip_bfloat16* __restrict__ qkv,
                 __hip_bfloat16* __restrict__ out) {
  __shared__ alignas(16) __hip_bfloat16 sK[32 * 64];        // [tok][dh]
  __shared__ alignas(16) __hip_bfloat16 sVT[64 * 40];       // [dh][tok] pad->40
  __shared__ alignas(16) __hip_bfloat16 sP[4 * 16 * 40];    // per-wave [q][tok]
  const int t = threadIdx.x;
  const int wv = t >> 6, l = t & 63;
  const int lr = l & 15, lk = (l >> 4) * 8;
  const int q0 = blockIdx.x * 64;
  const int hh = blockIdx.y;
  const int b = blockIdx.z;
  const size_t rowbase = (size_t)b * LL;
  const int qw = q0 + wv * 16;

  // Q fragments (A operand): row=lr, k-octet=lk, two dh halves
  bf16x8 qa[2];
  {
    const __hip_bfloat16* qp = qkv + (rowbase + qw + lr) * NQKV + hh * (3 * DHH);
    qa[0] = *(const bf16x8*)(qp + lk);
    qa[1] = *(const bf16x8*)(qp + 32 + lk);
  }

  f32x4 o[4] = {};
  float mrun[4] = {-INFINITY, -INFINITY, -INFINITY, -INFINITY};
  float lrun[4] = {0.f, 0.f, 0.f, 0.f};

  const int nt = q0 / 32 + 2;
  const int stok = t >> 3;          // 0..31
  const int sd = (t & 7) * 8;       // dh octet
  const __hip_bfloat16* gK = qkv + (rowbase + stok) * NQKV + hh * (3 * DHH) + DHH + sd;
  const __hip_bfloat16* gV = qkv + (rowbase + stok) * NQKV + hh * (3 * DHH) + 2 * DHH + sd;
  char* ldsK = (char*)sK + wv * 1024;

  for (int kt = 0; kt < nt; ++kt) {
    const int t0 = kt * 32;
    // stage K tile [32][64] via global_load_lds (linear)
    gload_lds16(gK + (size_t)t0 * NQKV, ldsK);
    // stage V^T via register transpose
    {
      union { int4 v; __hip_bfloat16 h8[8]; } u;
      u.v = *(const int4*)(gV + (size_t)t0 * NQKV);
#pragma unroll
      for (int j = 0; j < 8; ++j)
        sVT[(sd + j) * 40 + stok] = u.h8[j];
    }
    __syncthreads();
    if (t0 <= qw + 15) {            // wave-uniform causal skip
      // S = Q K^T  (16q x 32tok)
      f32x4 s[2];
#pragma unroll
      for (int th = 0; th < 2; ++th) {
        bf16x8 kb0 = *(const bf16x8*)(sK + (th * 16 + lr) * 64 + lk);
        bf16x8 kb1 = *(const bf16x8*)(sK + (th * 16 + lr) * 64 + 32 + lk);
        f32x4 z = {0.f, 0.f, 0.f, 0.f};
        z = MFMA16(qa[0], kb0, z);
        z = MFMA16(qa[1], kb1, z);
        s[th] = z;
      }
      const bool edge = (t0 + 31 > qw);
#pragma unroll
      for (int th = 0; th < 2; ++th) {
#pragma unroll
        for (int r = 0; r < 4; ++r) {
          float v = s[th][r] * 0.125f;   // 1/sqrt(64)
          if (edge) {
            const int tok = t0 + th * 16 + lr;
            const int qr = qw + (l >> 4) * 4 + r;
            if (tok > qr) v = -INFINITY;
          }
          s[th][r] = v;
        }
      }
      // online softmax per row (4 rows/lane), row-reduce over 16 lanes
#pragma unroll
      for (int r = 0; r < 4; ++r) {
        float m = fmaxf(s[0][r], s[1][r]);
#pragma unroll
        for (int off = 8; off >= 1; off >>= 1)
          m = fmaxf(m, __shfl_xor(m, off));
        const float mnew = fmaxf(mrun[r], m);
        const float corr = __expf(mrun[r] - mnew);
        const float p0 = __expf(s[0][r] - mnew);
        const float p1 = __expf(s[1][r] - mnew);
        float rs = p0 + p1;
#pragma unroll
        for (int off = 8; off >= 1; off >>= 1)
          rs += __shfl_xor(rs, off);
        lrun[r] = lrun[r] * corr + rs;
        mrun[r] = mnew;
        const int q = (l >> 4) * 4 + r;
        sP[wv * 640 + q * 40 + lr]      = __float2bfloat16(p0);
        sP[wv * 640 + q * 40 + 16 + lr] = __float2bfloat16(p1);
#pragma unroll
        for (int ni = 0; ni < 4; ++ni) o[ni][r] *= corr;
      }
      // PV: O += P(16x32) V(32x64)
      bf16x8 pf = *(const bf16x8*)(sP + wv * 640 + lr * 40 + lk);
#pragma unroll
      for (int ni = 0; ni < 4; ++ni) {
        bf16x8 vb = *(const bf16x8*)(sVT + (ni * 16 + lr) * 40 + lk);
        o[ni] = MFMA16(pf, vb, o[ni]);
      }
    }
    __syncthreads();
  }

  // normalize + write
#pragma unroll
  for (int r = 0; r < 4; ++r) {
    const float inv = 1.0f / lrun[r];
    const int qr = qw + (l >> 4) * 4 + r;
    __hip_bfloat16* op = out + (rowbase + qr) * (NHH * DHH) + hh * DHH;
#pragma unroll
    for (int ni = 0; ni < 4; ++ni)
      op[ni * 16 + lr] = __float2bfloat16(o[ni][r] * inv);
  }
}

// ---------------- launch ----------------
extern "C" void kernel_launch(void* const* d_in, const int* in_sizes, int n_in,
                              void* d_out, int out_size, void* d_ws, size_t ws_size,
                              hipStream_t stream) {
  (void)in_sizes; (void)n_in; (void)out_size; (void)ws_size;
  const float* x    = (const float*)d_in[0];
  const float* Wa   = (const float*)d_in[1];
  const float* Wout = (const float*)d_in[2];
  const float* bout = (const float*)d_in[3];
  const float* W1   = (const float*)d_in[4];
  const float* b1   = (const float*)d_in[5];
  const float* W2   = (const float*)d_in[6];
  const float* b2   = (const float*)d_in[7];
  const float* g1   = (const float*)d_in[8];
  const float* be1  = (const float*)d_in[9];
  const float* g2   = (const float*)d_in[10];
  const float* be2  = (const float*)d_in[11];

  char* ws = (char*)d_ws;
  __hip_bfloat16* WaT   = (__hip_bfloat16*)(ws + 0);         //  6291456 B
  __hip_bfloat16* WoutT = (__hip_bfloat16*)(ws + 6291456);   //  2097152 B
  __hip_bfloat16* W1T   = (__hip_bfloat16*)(ws + 8388608);   //  8388608 B (HID x E)
  __hip_bfloat16* W2T   = (__hip_bfloat16*)(ws + 16777216);  //  8388608 B (E x HID)
  __hip_bfloat16* o1    = (__hip_bfloat16*)(ws + 25165824);  //  8388608 B
  __hip_bfloat16* qkv   = (__hip_bfloat16*)(ws + 33554432);  // 25165824 B
  __hip_bfloat16* hbuf  = (__hip_bfloat16*)(ws + 25165824);  // reuse o1+qkv (33554432 B)
  __hip_bfloat16* attnb = (__hip_bfloat16*)(ws + 58720256);  //  8388608 B
  __hip_bfloat16* ln2b  = (__hip_bfloat16*)(ws + 58720256);  // reuse attnb
  float*          ybuf  = (float*)(ws + 67108864);           // 16777216 B -> total 83886080

  // weights -> bf16, transposed (N x K) so MFMA B-frags are contiguous
  convT_kernel<<<dim3(NQKV/32, EE/32), 256, 0, stream>>>(Wa, WaT, EE, NQKV);
  convT_kernel<<<dim3(EE/32, EE/32), 256, 0, stream>>>(Wout, WoutT, EE, EE);
  convT_kernel<<<dim3(HIDD/32, EE/32), 256, 0, stream>>>(W1, W1T, EE, HIDD);
  convT_kernel<<<dim3(EE/32, HIDD/32), 256, 0, stream>>>(W2, W2T, HIDD, EE);
  // LN1: x -> o1 (bf16)
  ln_kernel<<<MTOK, 256, 0, stream>>>(x, g1, be1, o1);
  // QKV projection
  gemm_kernel<1,0,0><<<dim3(NQKV/128, MTOK/128), 256, 0, stream>>>(
      o1, WaT, qkv, nullptr, nullptr, MTOK, NQKV, EE);
  // attention
  attn_kernel<<<dim3(LL/64, NHH, BB), 256, 0, stream>>>(qkv, attnb);
  // out projection + bout + residual x -> y (fp32)
  gemm_kernel<0,1,1><<<dim3(EE/128, MTOK/128), 256, 0, stream>>>(
      attnb, WoutT, ybuf, bout, x, MTOK, EE, EE);
  // LN2: y -> ln2b (bf16)
  ln_kernel<<<MTOK, 256, 0, stream>>>(ybuf, g2, be2, ln2b);
  // FFN1 (+b1) -> hbuf (bf16)
  gemm_kernel<1,1,0><<<dim3(HIDD/128, MTOK/128), 256, 0, stream>>>(
      ln2b, W1T, hbuf, b1, nullptr, MTOK, HIDD, EE);
  // FFN2 (+b2) + residual x -> d_out (fp32)
  gemm_kernel<0,1,1><<<dim3(EE/128, MTOK/128), 256, 0, stream>>>(
      hbuf, W2T, (float*)d_out, b2, x, MTOK, EE, HIDD);
}

// Round 2
// 437.671 us; speedup vs baseline: 1.3017x; 1.3017x over previous
//
#include <hip/hip_runtime.h>
#include <hip/hip_bf16.h>

// ---------------- problem dims (fixed) ----------------
#define BB 2
#define LL 2048
#define EE 1024
#define NHH 16
#define DHH 64
#define HIDD 4096
#define MTOK (BB*LL)          // 4096 tokens
#define NQKV (NHH*3*DHH)      // 3072

typedef __attribute__((ext_vector_type(8))) short bf16x8;   // 8 bf16 in 4 VGPRs
typedef __attribute__((ext_vector_type(4))) float f32x4;

#define MFMA16(a,b,c) __builtin_amdgcn_mfma_f32_16x16x32_bf16(a,b,c,0,0,0)

static __device__ __forceinline__ void gload_lds16(const void* g, void* lds) {
  __builtin_amdgcn_global_load_lds(
      (const __attribute__((address_space(1))) unsigned int*)g,
      (__attribute__((address_space(3))) unsigned int*)lds, 16, 0, 0);
}

// ---------------- weight fp32 -> bf16 transpose-convert ----------------
// W: K x N row-major f32  ->  WT: N x K row-major bf16
__global__ __launch_bounds__(256)
void convT_kernel(const float* __restrict__ W, __hip_bfloat16* __restrict__ WT,
                  int K, int N) {
  __shared__ float tile[32][33];
  const int tx = threadIdx.x & 31, ty = threadIdx.x >> 5;   // ty 0..7
  const int n0 = blockIdx.x * 32, k0 = blockIdx.y * 32;
#pragma unroll
  for (int i = 0; i < 4; ++i)
    tile[ty + i*8][tx] = W[(size_t)(k0 + ty + i*8) * N + n0 + tx];
  __syncthreads();
#pragma unroll
  for (int i = 0; i < 4; ++i)
    WT[(size_t)(n0 + ty + i*8) * K + k0 + tx] = __float2bfloat16(tile[tx][ty + i*8]);
}

// ---------------- V transpose: qkv -> VT[bh][dh][L] (bf16) ----------------
__global__ __launch_bounds__(256)
void vtrans_kernel(const __hip_bfloat16* __restrict__ qkv,
                   __hip_bfloat16* __restrict__ VT) {
  __shared__ ushort tile[32][34];
  const int tx = threadIdx.x & 31, ty = threadIdx.x >> 5;   // ty 0..7
  const int tok0 = blockIdx.x * 32;
  const int dh0  = blockIdx.y * 32;
  const int bh   = blockIdx.z;              // b*NH + h
  const int b = bh >> 4, h = bh & 15;
  const ushort* src = (const ushort*)qkv;
#pragma unroll
  for (int i = 0; i < 4; ++i)
    tile[ty + i*8][tx] =
      src[(size_t)(b*LL + tok0 + ty + i*8) * NQKV + h*192 + 128 + dh0 + tx];
  __syncthreads();
  ushort* dst = (ushort*)VT;
#pragma unroll
  for (int i = 0; i < 4; ++i)
    dst[(size_t)(bh*DHH + dh0 + ty + i*8) * LL + tok0 + tx] = tile[tx][ty + i*8];
}

// ---------------- LayerNorm (fp32 in, bf16 out), row = 1024 ----------------
__global__ __launch_bounds__(256)
void ln_kernel(const float* __restrict__ in, const float* __restrict__ g,
               const float* __restrict__ be, __hip_bfloat16* __restrict__ out) {
  const int row = blockIdx.x;
  const int t = threadIdx.x;
  const float4 v = ((const float4*)(in + (size_t)row * EE))[t];
  float s = v.x + v.y + v.z + v.w;
  float q = v.x*v.x + v.y*v.y + v.z*v.z + v.w*v.w;
#pragma unroll
  for (int off = 32; off >= 1; off >>= 1) {
    s += __shfl_xor(s, off);
    q += __shfl_xor(q, off);
  }
  __shared__ float ps[4], pq[4];
  if ((t & 63) == 0) { ps[t >> 6] = s; pq[t >> 6] = q; }
  __syncthreads();
  s = ps[0] + ps[1] + ps[2] + ps[3];
  q = pq[0] + pq[1] + pq[2] + pq[3];
  const float mean = s * (1.0f / EE);
  const float rstd = rsqrtf(q * (1.0f / EE) - mean * mean + 1e-5f);
  const float4 gg = ((const float4*)g)[t];
  const float4 bb = ((const float4*)be)[t];
  union { ushort4 u; __hip_bfloat16 h[4]; } o;
  o.h[0] = __float2bfloat16((v.x - mean) * rstd * gg.x + bb.x);
  o.h[1] = __float2bfloat16((v.y - mean) * rstd * gg.y + bb.y);
  o.h[2] = __float2bfloat16((v.z - mean) * rstd * gg.z + bb.z);
  o.h[3] = __float2bfloat16((v.w - mean) * rstd * gg.w + bb.w);
  ((ushort4*)(out + (size_t)row * EE))[t] = o.u;
}

// ---------------- bf16 MFMA GEMM: C = A(MxK) * BT(NxK)^T ----------------
// 128x128 tile, BK=32, 256 threads (4 waves, 2x2 of 64x64), m97 structure.
template<int OUT_BF16, int HAS_BIAS, int HAS_RES>
__global__ __launch_bounds__(256)
void gemm_kernel(const __hip_bfloat16* __restrict__ A,
                 const __hip_bfloat16* __restrict__ BT,
                 void* __restrict__ Cv,
                 const float* __restrict__ bias,
                 const float* __restrict__ res,
                 int M, int N, int K) {
  __shared__ alignas(16) __hip_bfloat16 sA[128 * 32];
  __shared__ alignas(16) __hip_bfloat16 sB[128 * 32];
  const int t = threadIdx.x;
  const int wv = t >> 6;
  const int l = t & 63;
  const int lr = l & 15;            // row/col within a 16-group
  const int lk = (l >> 4) * 8;      // k octet
  const int m0 = blockIdx.y * 128;
  const int n0 = blockIdx.x * 128;
  const int wrow = (wv >> 1) * 64;
  const int wcol = (wv & 1) * 64;

  const int srow = t >> 2;
  const int scol = (t & 3) * 8;
  const __hip_bfloat16* gA = A + (size_t)(m0 + srow) * K + scol;
  const __hip_bfloat16* gB = BT + (size_t)(n0 + srow) * K + scol;
  char* ldsA = (char*)sA + wv * 1024;
  char* ldsB = (char*)sB + wv * 1024;

  f32x4 acc[4][4] = {};

  for (int k0 = 0; k0 < K; k0 += 32) {
    gload_lds16(gA + k0, ldsA);
    gload_lds16(gA + (size_t)64 * K + k0, ldsA + 4096);
    gload_lds16(gB + k0, ldsB);
    gload_lds16(gB + (size_t)64 * K + k0, ldsB + 4096);
    __syncthreads();
    bf16x8 af[4], bfv[4];
#pragma unroll
    for (int mi = 0; mi < 4; ++mi)
      af[mi] = *(const bf16x8*)(sA + (wrow + mi * 16 + lr) * 32 + lk);
#pragma unroll
    for (int ni = 0; ni < 4; ++ni)
      bfv[ni] = *(const bf16x8*)(sB + (wcol + ni * 16 + lr) * 32 + lk);
#pragma unroll
    for (int mi = 0; mi < 4; ++mi)
#pragma unroll
      for (int ni = 0; ni < 4; ++ni)
        acc[mi][ni] = MFMA16(af[mi], bfv[ni], acc[mi][ni]);
    __syncthreads();
  }

  const int rbase = (l >> 4) * 4;
#pragma unroll
  for (int mi = 0; mi < 4; ++mi) {
#pragma unroll
    for (int ni = 0; ni < 4; ++ni) {
#pragma unroll
      for (int r = 0; r < 4; ++r) {
        const int row = m0 + wrow + mi * 16 + rbase + r;
        const int col = n0 + wcol + ni * 16 + lr;
        float v = acc[mi][ni][r];
        if constexpr (HAS_BIAS) v += bias[col];
        if constexpr (HAS_RES)  v += res[(size_t)row * N + col];
        if constexpr (OUT_BF16)
          ((__hip_bfloat16*)Cv)[(size_t)row * N + col] = __float2bfloat16(v);
        else
          ((float*)Cv)[(size_t)row * N + col] = v;
      }
    }
  }
}

// ---------------- causal flash attention v2 ----------------
// grid (L/128, NH, B), 256 threads = 4 independent waves, 32 q-rows each.
// No __syncthreads. K read direct from qkv (L2-resident), V from pre-transposed
// VT[bh][dh][L]. Only P round-trips through wave-private LDS.
__global__ __launch_bounds__(256)
void attn_kernel(const __hip_bfloat16* __restrict__ qkv,
                 const __hip_bfloat16* __restrict__ VT,
                 __hip_bfloat16* __restrict__ out) {
  __shared__ alignas(16) __hip_bfloat16 sP[4][32 * 72];   // per-wave [32q][64tok pad72]
  const int t = threadIdx.x;
  const int wv = t >> 6, l = t & 63;
  const int lr = l & 15, lg = l >> 4, lk = lg * 8;
  const int hh = blockIdx.y, b = blockIdx.z;
  // complementary-length pairing: batch 1 reverses q-tile order so co-resident
  // blocks (fid, fid+256) sum to a constant causal length
  int qx = blockIdx.x;
  if (b == 1) qx = 15 - qx;
  const int qw = qx * 128 + wv * 32;
  const size_t rowbase = (size_t)b * LL;
  const int hoff = hh * (3 * DHH);
  const __hip_bfloat16* vt = VT + (size_t)((b * NHH + hh) * DHH) * LL;

  // Q fragments: A[row=q][k=dh], row=lr, k-octet lk, two dh halves
  bf16x8 qa[2][2];
#pragma unroll
  for (int rg = 0; rg < 2; ++rg)
#pragma unroll
    for (int h = 0; h < 2; ++h)
      qa[rg][h] = *(const bf16x8*)(qkv + (rowbase + qw + rg*16 + lr) * NQKV
                                   + hoff + h*32 + lk);

  f32x4 o[2][4] = {};
  float mrun[2][4], lrun[2][4];
#pragma unroll
  for (int rg = 0; rg < 2; ++rg)
#pragma unroll
    for (int r = 0; r < 4; ++r) { mrun[rg][r] = -INFINITY; lrun[rg][r] = 0.f; }

  __hip_bfloat16* sp = sP[wv];
  const int nt = (qw + 95) >> 6;      // ceil((qw+32)/64) KV tiles of 64

  for (int kt = 0; kt < nt; ++kt) {
    const int t0 = kt * 64;
    // V fragments for PV (issued early; L2-hit, hidden under QK^T + softmax)
    bf16x8 vb[4][2];
#pragma unroll
    for (int ni = 0; ni < 4; ++ni)
#pragma unroll
      for (int ks = 0; ks < 2; ++ks)
        vb[ni][ks] = *(const bf16x8*)(vt + (size_t)(ni*16 + lr) * LL + t0 + ks*32 + lk);

    // S = Q K^T : B-frag = K^T[dh][tok] -> lane reads K[t0+tg*16+lr][lk..+8]
    f32x4 s[2][4];
#pragma unroll
    for (int tg = 0; tg < 4; ++tg) {
      const __hip_bfloat16* kp = qkv + (rowbase + t0 + tg*16 + lr) * NQKV + hoff + DHH;
      bf16x8 kb0 = *(const bf16x8*)(kp + lk);
      bf16x8 kb1 = *(const bf16x8*)(kp + 32 + lk);
#pragma unroll
      for (int rg = 0; rg < 2; ++rg) {
        f32x4 z = {0.f, 0.f, 0.f, 0.f};
        z = MFMA16(qa[rg][0], kb0, z);
        z = MFMA16(qa[rg][1], kb1, z);
        s[rg][tg] = z;
      }
    }

    const bool edge = (kt == nt - 1);
#pragma unroll
    for (int rg = 0; rg < 2; ++rg)
#pragma unroll
      for (int tg = 0; tg < 4; ++tg)
#pragma unroll
        for (int r = 0; r < 4; ++r) {
          float v = s[rg][tg][r] * 0.125f;     // 1/sqrt(64)
          if (edge) {
            const int tok = t0 + tg*16 + lr;
            const int qr  = qw + rg*16 + lg*4 + r;
            if (tok > qr) v = -INFINITY;
          }
          s[rg][tg][r] = v;
        }

    // online softmax per row (8 rows/lane-quad), reduce over 16 lanes
#pragma unroll
    for (int rg = 0; rg < 2; ++rg)
#pragma unroll
      for (int r = 0; r < 4; ++r) {
        float m = fmaxf(fmaxf(s[rg][0][r], s[rg][1][r]),
                        fmaxf(s[rg][2][r], s[rg][3][r]));
#pragma unroll
        for (int off = 8; off >= 1; off >>= 1)
          m = fmaxf(m, __shfl_xor(m, off));
        const float mnew = fmaxf(mrun[rg][r], m);
        const float corr = __expf(mrun[rg][r] - mnew);
        const float p0 = __expf(s[rg][0][r] - mnew);
        const float p1 = __expf(s[rg][1][r] - mnew);
        const float p2 = __expf(s[rg][2][r] - mnew);
        const float p3 = __expf(s[rg][3][r] - mnew);
        float rs = (p0 + p1) + (p2 + p3);
#pragma unroll
        for (int off = 8; off >= 1; off >>= 1)
          rs += __shfl_xor(rs, off);
        lrun[rg][r] = lrun[rg][r] * corr + rs;
        mrun[rg][r] = mnew;
        const int q = rg*16 + lg*4 + r;
        sp[q*72 +      lr] = __float2bfloat16(p0);
        sp[q*72 + 16 + lr] = __float2bfloat16(p1);
        sp[q*72 + 32 + lr] = __float2bfloat16(p2);
        sp[q*72 + 48 + lr] = __float2bfloat16(p3);
#pragma unroll
        for (int ni = 0; ni < 4; ++ni) o[rg][ni][r] *= corr;
      }

    // PV: O += P(32x64) V(64x64); A-frag P[q=lr][tok octet], same-wave LDS
    // round-trip (compiler inserts lgkmcnt; no barrier needed, wave-private)
#pragma unroll
    for (int rg = 0; rg < 2; ++rg) {
      bf16x8 pf0 = *(const bf16x8*)(sp + (rg*16 + lr)*72 + lk);
      bf16x8 pf1 = *(const bf16x8*)(sp + (rg*16 + lr)*72 + 32 + lk);
#pragma unroll
      for (int ni = 0; ni < 4; ++ni) {
        o[rg][ni] = MFMA16(pf0, vb[ni][0], o[rg][ni]);
        o[rg][ni] = MFMA16(pf1, vb[ni][1], o[rg][ni]);
      }
    }
  }

  // normalize + write
#pragma unroll
  for (int rg = 0; rg < 2; ++rg)
#pragma unroll
    for (int r = 0; r < 4; ++r) {
      const float inv = 1.0f / lrun[rg][r];
      const int qr = qw + rg*16 + lg*4 + r;
      __hip_bfloat16* op = out + (rowbase + qr) * (NHH * DHH) + hh * DHH;
#pragma unroll
      for (int ni = 0; ni < 4; ++ni)
        op[ni*16 + lr] = __float2bfloat16(o[rg][ni][r] * inv);
    }
}

// ---------------- launch ----------------
extern "C" void kernel_launch(void* const* d_in, const int* in_sizes, int n_in,
                              void* d_out, int out_size, void* d_ws, size_t ws_size,
                              hipStream_t stream) {
  (void)in_sizes; (void)n_in; (void)out_size; (void)ws_size;
  const float* x    = (const float*)d_in[0];
  const float* Wa   = (const float*)d_in[1];
  const float* Wout = (const float*)d_in[2];
  const float* bout = (const float*)d_in[3];
  const float* W1   = (const float*)d_in[4];
  const float* b1   = (const float*)d_in[5];
  const float* W2   = (const float*)d_in[6];
  const float* b2   = (const float*)d_in[7];
  const float* g1   = (const float*)d_in[8];
  const float* be1  = (const float*)d_in[9];
  const float* g2   = (const float*)d_in[10];
  const float* be2  = (const float*)d_in[11];

  char* ws = (char*)d_ws;
  __hip_bfloat16* WaT   = (__hip_bfloat16*)(ws + 0);         //  6291456 B
  __hip_bfloat16* WoutT = (__hip_bfloat16*)(ws + 6291456);   //  2097152 B
  __hip_bfloat16* W1T   = (__hip_bfloat16*)(ws + 8388608);   //  8388608 B (HID x E)
  __hip_bfloat16* W2T   = (__hip_bfloat16*)(ws + 16777216);  //  8388608 B (E x HID)
  __hip_bfloat16* o1    = (__hip_bfloat16*)(ws + 25165824);  //  8388608 B
  __hip_bfloat16* qkv   = (__hip_bfloat16*)(ws + 33554432);  // 25165824 B
  __hip_bfloat16* hbuf  = (__hip_bfloat16*)(ws + 25165824);  // reuse o1+qkv
  __hip_bfloat16* attnb = (__hip_bfloat16*)(ws + 58720256);  //  8388608 B
  __hip_bfloat16* ln2b  = (__hip_bfloat16*)(ws + 58720256);  // reuse attnb
  float*          ybuf  = (float*)(ws + 67108864);           // 16777216 B
  __hip_bfloat16* VT    = (__hip_bfloat16*)(ws + 67108864);  // 8 MB, aliases ybuf
                                                             // (dead before Wout gemm)

  // weights -> bf16, transposed (N x K) so MFMA B-frags are contiguous
  convT_kernel<<<dim3(NQKV/32, EE/32), 256, 0, stream>>>(Wa, WaT, EE, NQKV);
  convT_kernel<<<dim3(EE/32, EE/32), 256, 0, stream>>>(Wout, WoutT, EE, EE);
  convT_kernel<<<dim3(HIDD/32, EE/32), 256, 0, stream>>>(W1, W1T, EE, HIDD);
  convT_kernel<<<dim3(EE/32, HIDD/32), 256, 0, stream>>>(W2, W2T, HIDD, EE);
  // LN1: x -> o1 (bf16)
  ln_kernel<<<MTOK, 256, 0, stream>>>(x, g1, be1, o1);
  // QKV projection
  gemm_kernel<1,0,0><<<dim3(NQKV/128, MTOK/128), 256, 0, stream>>>(
      o1, WaT, qkv, nullptr, nullptr, MTOK, NQKV, EE);
  // V transpose for attention PV fragments
  vtrans_kernel<<<dim3(LL/32, DHH/32, BB*NHH), 256, 0, stream>>>(qkv, VT);
  // attention
  attn_kernel<<<dim3(LL/128, NHH, BB), 256, 0, stream>>>(qkv, VT, attnb);
  // out projection + bout + residual x -> y (fp32)
  gemm_kernel<0,1,1><<<dim3(EE/128, MTOK/128), 256, 0, stream>>>(
      attnb, WoutT, ybuf, bout, x, MTOK, EE, EE);
  // LN2: y -> ln2b (bf16)
  ln_kernel<<<MTOK, 256, 0, stream>>>(ybuf, g2, be2, ln2b);
  // FFN1 (+b1) -> hbuf (bf16)
  gemm_kernel<1,1,0><<<dim3(HIDD/128, MTOK/128), 256, 0, stream>>>(
      ln2b, W1T, hbuf, b1, nullptr, MTOK, HIDD, EE);
  // FFN2 (+b2) + residual x -> d_out (fp32)
  gemm_kernel<0,1,1><<<dim3(EE/128, MTOK/128), 256, 0, stream>>>(
      hbuf, W2T, (float*)d_out, b2, x, MTOK, EE, HIDD);
}

// Round 3
// 402.444 us; speedup vs baseline: 1.4157x; 1.0875x over previous
//
#include <hip/hip_runtime.h>
#include <hip/hip_bf16.h>

// ---------------- problem dims (fixed) ----------------
#define BB 2
#define LL 2048
#define EE 1024
#define NHH 16
#define DHH 64
#define HIDD 4096
#define MTOK (BB*LL)          // 4096 tokens
#define NQKV (NHH*3*DHH)      // 3072

typedef __attribute__((ext_vector_type(8))) short bf16x8;   // 8 bf16 in 4 VGPRs
typedef __attribute__((ext_vector_type(4))) float f32x4;

#define MFMA16(a,b,c) __builtin_amdgcn_mfma_f32_16x16x32_bf16(a,b,c,0,0,0)

static __device__ __forceinline__ void gload_lds16(const void* g, void* lds) {
  __builtin_amdgcn_global_load_lds(
      (const __attribute__((address_space(1))) unsigned int*)g,
      (__attribute__((address_space(3))) unsigned int*)lds, 16, 0, 0);
}

// ---------------- weight fp32 -> bf16 transpose-convert ----------------
__global__ __launch_bounds__(256)
void convT_kernel(const float* __restrict__ W, __hip_bfloat16* __restrict__ WT,
                  int K, int N) {
  __shared__ float tile[32][33];
  const int tx = threadIdx.x & 31, ty = threadIdx.x >> 5;
  const int n0 = blockIdx.x * 32, k0 = blockIdx.y * 32;
#pragma unroll
  for (int i = 0; i < 4; ++i)
    tile[ty + i*8][tx] = W[(size_t)(k0 + ty + i*8) * N + n0 + tx];
  __syncthreads();
#pragma unroll
  for (int i = 0; i < 4; ++i)
    WT[(size_t)(n0 + ty + i*8) * K + k0 + tx] = __float2bfloat16(tile[tx][ty + i*8]);
}

// ---------------- V transpose: qkv -> VT[bh][dh][L] ----------------
__global__ __launch_bounds__(256)
void vtrans_kernel(const __hip_bfloat16* __restrict__ qkv,
                   __hip_bfloat16* __restrict__ VT) {
  __shared__ ushort tile[32][34];
  const int tx = threadIdx.x & 31, ty = threadIdx.x >> 5;
  const int tok0 = blockIdx.x * 32;
  const int dh0  = blockIdx.y * 32;
  const int bh   = blockIdx.z;
  const int b = bh >> 4, h = bh & 15;
  const ushort* src = (const ushort*)qkv;
#pragma unroll
  for (int i = 0; i < 4; ++i)
    tile[ty + i*8][tx] =
      src[(size_t)(b*LL + tok0 + ty + i*8) * NQKV + h*192 + 128 + dh0 + tx];
  __syncthreads();
  ushort* dst = (ushort*)VT;
#pragma unroll
  for (int i = 0; i < 4; ++i)
    dst[(size_t)(bh*DHH + dh0 + ty + i*8) * LL + tok0 + tx] = tile[tx][ty + i*8];
}

// ---------------- LayerNorm (fp32 in, bf16 out), row = 1024 ----------------
__global__ __launch_bounds__(256)
void ln_kernel(const float* __restrict__ in, const float* __restrict__ g,
               const float* __restrict__ be, __hip_bfloat16* __restrict__ out) {
  const int row = blockIdx.x;
  const int t = threadIdx.x;
  const float4 v = ((const float4*)(in + (size_t)row * EE))[t];
  float s = v.x + v.y + v.z + v.w;
  float q = v.x*v.x + v.y*v.y + v.z*v.z + v.w*v.w;
#pragma unroll
  for (int off = 32; off >= 1; off >>= 1) {
    s += __shfl_xor(s, off);
    q += __shfl_xor(q, off);
  }
  __shared__ float ps[4], pq[4];
  if ((t & 63) == 0) { ps[t >> 6] = s; pq[t >> 6] = q; }
  __syncthreads();
  s = ps[0] + ps[1] + ps[2] + ps[3];
  q = pq[0] + pq[1] + pq[2] + pq[3];
  const float mean = s * (1.0f / EE);
  const float rstd = rsqrtf(q * (1.0f / EE) - mean * mean + 1e-5f);
  const float4 gg = ((const float4*)g)[t];
  const float4 bb = ((const float4*)be)[t];
  union { ushort4 u; __hip_bfloat16 h[4]; } o;
  o.h[0] = __float2bfloat16((v.x - mean) * rstd * gg.x + bb.x);
  o.h[1] = __float2bfloat16((v.y - mean) * rstd * gg.y + bb.y);
  o.h[2] = __float2bfloat16((v.z - mean) * rstd * gg.z + bb.z);
  o.h[3] = __float2bfloat16((v.w - mean) * rstd * gg.w + bb.w);
  ((ushort4*)(out + (size_t)row * EE))[t] = o.u;
}

// ---------------- GEMM body: C = A(Mx K) * BT(N x K)^T ----------------
// 128 x BN tile, 2-phase prefetch double-buffer, XCD-swizzled block mapping.
// BN = 128 (4 n-frags/wave) or 64 (2 n-frags/wave, higher grid occupancy).
template<int BN, int OUT_BF16, int HAS_BIAS, int HAS_RES>
__device__ __forceinline__ void gemm_body(
    const __hip_bfloat16* __restrict__ A, const __hip_bfloat16* __restrict__ BT,
    void* __restrict__ Cv, const float* __restrict__ bias,
    const float* __restrict__ res, int M, int N, int K, int lda, int ldb) {
  constexpr int NF = BN / 32;               // n-frags per wave
  __shared__ alignas(16) __hip_bfloat16 sA[2][128 * 32];
  __shared__ alignas(16) __hip_bfloat16 sB[2][BN * 32];
  const int t = threadIdx.x;
  const int wv = t >> 6, l = t & 63;
  const int lr = l & 15, lk = (l >> 4) * 8;

  // XCD-aware swizzle (grids are multiples of 8): contiguous chunk per XCD
  const int nwg = gridDim.x * gridDim.y;
  int wg = blockIdx.y * gridDim.x + blockIdx.x;
  wg = (wg & 7) * (nwg >> 3) + (wg >> 3);
  const int bx = wg % gridDim.x, by = wg / gridDim.x;
  const int m0 = by * 128, n0 = bx * BN;

  const int wrow = (wv >> 1) * 64;
  const int wcol = (wv & 1) * (BN / 2);
  const int srow = t >> 2, scol = (t & 3) * 8;
  const __hip_bfloat16* gA = A + (size_t)(m0 + srow) * lda + scol;
  const __hip_bfloat16* gB = BT + (size_t)(n0 + srow) * ldb + scol;

  auto stage = [&](int buf, int k0) {
    char* dA = (char*)(&sA[buf][0]) + wv * 1024;
    gload_lds16(gA + k0, dA);
    gload_lds16(gA + (size_t)64 * lda + k0, dA + 4096);
    char* dB = (char*)(&sB[buf][0]) + wv * 1024;
    gload_lds16(gB + k0, dB);
    if constexpr (BN == 128)
      gload_lds16(gB + (size_t)64 * ldb + k0, dB + 4096);
  };

  f32x4 acc[4][NF] = {};

  auto compute = [&](int buf) {
    bf16x8 af[4], bfv[NF];
#pragma unroll
    for (int mi = 0; mi < 4; ++mi)
      af[mi] = *(const bf16x8*)(&sA[buf][(wrow + mi * 16 + lr) * 32 + lk]);
#pragma unroll
    for (int ni = 0; ni < NF; ++ni)
      bfv[ni] = *(const bf16x8*)(&sB[buf][(wcol + ni * 16 + lr) * 32 + lk]);
#pragma unroll
    for (int mi = 0; mi < 4; ++mi)
#pragma unroll
      for (int ni = 0; ni < NF; ++ni)
        acc[mi][ni] = MFMA16(af[mi], bfv[ni], acc[mi][ni]);
  };

  // 2-phase: stage(next) issued BEFORE compute(cur); one barrier per K-step.
  stage(0, 0);
  __syncthreads();
  for (int k0 = 0; k0 < K; k0 += 64) {
    stage(1, k0 + 32);
    compute(0);
    __syncthreads();
    if (k0 + 64 < K) stage(0, k0 + 64);
    compute(1);
    __syncthreads();
  }

  const int rbase = (l >> 4) * 4;
#pragma unroll
  for (int mi = 0; mi < 4; ++mi) {
#pragma unroll
    for (int ni = 0; ni < NF; ++ni) {
#pragma unroll
      for (int r = 0; r < 4; ++r) {
        const int row = m0 + wrow + mi * 16 + rbase + r;
        const int col = n0 + wcol + ni * 16 + lr;
        float v = acc[mi][ni][r];
        if constexpr (HAS_BIAS) v += bias[col];
        if constexpr (HAS_RES)  v += res[(size_t)row * N + col];
        if constexpr (OUT_BF16)
          ((__hip_bfloat16*)Cv)[(size_t)row * N + col] = __float2bfloat16(v);
        else
          ((float*)Cv)[(size_t)row * N + col] = v;
      }
    }
  }
}

// Named wrappers so rocprof disambiguates stages
__global__ __launch_bounds__(256)
void gemm_qkv(const __hip_bfloat16* A, const __hip_bfloat16* BT, __hip_bfloat16* C) {
  gemm_body<128,1,0,0>(A, BT, C, nullptr, nullptr, MTOK, NQKV, EE, EE, EE);
}
__global__ __launch_bounds__(256)
void gemm_wout(const __hip_bfloat16* A, const __hip_bfloat16* BT, float* C,
               const float* bias, const float* res) {
  gemm_body<128,0,1,1>(A, BT, C, bias, res, MTOK, EE, EE, EE, EE);
}
__global__ __launch_bounds__(256)
void gemm_ffn1(const __hip_bfloat16* A, const __hip_bfloat16* BT, __hip_bfloat16* C,
               const float* bias) {
  gemm_body<128,1,1,0>(A, BT, C, bias, nullptr, MTOK, HIDD, EE, EE, EE);
}
// FFN2 split-K=2 partials, BN=64 tile for 4 blocks/CU
__global__ __launch_bounds__(256)
void gemm_ffn2p(const __hip_bfloat16* A, const __hip_bfloat16* BT,
                float* P0, float* P1) {
  const int ks = blockIdx.z;
  float* P = ks ? P1 : P0;
  gemm_body<64,0,0,0>(A + ks * 2048, BT + ks * 2048, P, nullptr, nullptr,
                      MTOK, EE, 2048, HIDD, HIDD);
}

// out = x + b2 + P0 + P1   (fp32, vectorized)
__global__ __launch_bounds__(256)
void ffn2_reduce(const float4* __restrict__ P0, const float4* __restrict__ P1,
                 const float4* __restrict__ x, const float* __restrict__ b2,
                 float4* __restrict__ out) {
  const int n4 = MTOK * EE / 4;
  for (int i = blockIdx.x * 256 + threadIdx.x; i < n4; i += 2048 * 256) {
    const float4 b = ((const float4*)b2)[i & 255];
    const float4 p = P0[i], q = P1[i], xx = x[i];
    float4 o;
    o.x = xx.x + b.x + p.x + q.x;
    o.y = xx.y + b.y + p.y + q.y;
    o.z = xx.z + b.z + p.z + q.z;
    o.w = xx.w + b.w + p.w + q.w;
    out[i] = o;
  }
}

// ---------------- causal flash attention (unchanged from r2) ----------------
__global__ __launch_bounds__(256)
void attn_kernel(const __hip_bfloat16* __restrict__ qkv,
                 const __hip_bfloat16* __restrict__ VT,
                 __hip_bfloat16* __restrict__ out) {
  __shared__ alignas(16) __hip_bfloat16 sP[4][32 * 72];
  const int t = threadIdx.x;
  const int wv = t >> 6, l = t & 63;
  const int lr = l & 15, lg = l >> 4, lk = lg * 8;
  const int hh = blockIdx.y, b = blockIdx.z;
  int qx = blockIdx.x;
  if (b == 1) qx = 15 - qx;
  const int qw = qx * 128 + wv * 32;
  const size_t rowbase = (size_t)b * LL;
  const int hoff = hh * (3 * DHH);
  const __hip_bfloat16* vt = VT + (size_t)((b * NHH + hh) * DHH) * LL;

  bf16x8 qa[2][2];
#pragma unroll
  for (int rg = 0; rg < 2; ++rg)
#pragma unroll
    for (int h = 0; h < 2; ++h)
      qa[rg][h] = *(const bf16x8*)(qkv + (rowbase + qw + rg*16 + lr) * NQKV
                                   + hoff + h*32 + lk);

  f32x4 o[2][4] = {};
  float mrun[2][4], lrun[2][4];
#pragma unroll
  for (int rg = 0; rg < 2; ++rg)
#pragma unroll
    for (int r = 0; r < 4; ++r) { mrun[rg][r] = -INFINITY; lrun[rg][r] = 0.f; }

  __hip_bfloat16* sp = sP[wv];
  const int nt = (qw + 95) >> 6;

  for (int kt = 0; kt < nt; ++kt) {
    const int t0 = kt * 64;
    bf16x8 vb[4][2];
#pragma unroll
    for (int ni = 0; ni < 4; ++ni)
#pragma unroll
      for (int ks = 0; ks < 2; ++ks)
        vb[ni][ks] = *(const bf16x8*)(vt + (size_t)(ni*16 + lr) * LL + t0 + ks*32 + lk);

    f32x4 s[2][4];
#pragma unroll
    for (int tg = 0; tg < 4; ++tg) {
      const __hip_bfloat16* kp = qkv + (rowbase + t0 + tg*16 + lr) * NQKV + hoff + DHH;
      bf16x8 kb0 = *(const bf16x8*)(kp + lk);
      bf16x8 kb1 = *(const bf16x8*)(kp + 32 + lk);
#pragma unroll
      for (int rg = 0; rg < 2; ++rg) {
        f32x4 z = {0.f, 0.f, 0.f, 0.f};
        z = MFMA16(qa[rg][0], kb0, z);
        z = MFMA16(qa[rg][1], kb1, z);
        s[rg][tg] = z;
      }
    }

    const bool edge = (kt == nt - 1);
#pragma unroll
    for (int rg = 0; rg < 2; ++rg)
#pragma unroll
      for (int tg = 0; tg < 4; ++tg)
#pragma unroll
        for (int r = 0; r < 4; ++r) {
          float v = s[rg][tg][r] * 0.125f;
          if (edge) {
            const int tok = t0 + tg*16 + lr;
            const int qr  = qw + rg*16 + lg*4 + r;
            if (tok > qr) v = -INFINITY;
          }
          s[rg][tg][r] = v;
        }

#pragma unroll
    for (int rg = 0; rg < 2; ++rg)
#pragma unroll
      for (int r = 0; r < 4; ++r) {
        float m = fmaxf(fmaxf(s[rg][0][r], s[rg][1][r]),
                        fmaxf(s[rg][2][r], s[rg][3][r]));
#pragma unroll
        for (int off = 8; off >= 1; off >>= 1)
          m = fmaxf(m, __shfl_xor(m, off));
        const float mnew = fmaxf(mrun[rg][r], m);
        const float corr = __expf(mrun[rg][r] - mnew);
        const float p0 = __expf(s[rg][0][r] - mnew);
        const float p1 = __expf(s[rg][1][r] - mnew);
        const float p2 = __expf(s[rg][2][r] - mnew);
        const float p3 = __expf(s[rg][3][r] - mnew);
        float rs = (p0 + p1) + (p2 + p3);
#pragma unroll
        for (int off = 8; off >= 1; off >>= 1)
          rs += __shfl_xor(rs, off);
        lrun[rg][r] = lrun[rg][r] * corr + rs;
        mrun[rg][r] = mnew;
        const int q = rg*16 + lg*4 + r;
        sp[q*72 +      lr] = __float2bfloat16(p0);
        sp[q*72 + 16 + lr] = __float2bfloat16(p1);
        sp[q*72 + 32 + lr] = __float2bfloat16(p2);
        sp[q*72 + 48 + lr] = __float2bfloat16(p3);
#pragma unroll
        for (int ni = 0; ni < 4; ++ni) o[rg][ni][r] *= corr;
      }

#pragma unroll
    for (int rg = 0; rg < 2; ++rg) {
      bf16x8 pf0 = *(const bf16x8*)(sp + (rg*16 + lr)*72 + lk);
      bf16x8 pf1 = *(const bf16x8*)(sp + (rg*16 + lr)*72 + 32 + lk);
#pragma unroll
      for (int ni = 0; ni < 4; ++ni) {
        o[rg][ni] = MFMA16(pf0, vb[ni][0], o[rg][ni]);
        o[rg][ni] = MFMA16(pf1, vb[ni][1], o[rg][ni]);
      }
    }
  }

#pragma unroll
  for (int rg = 0; rg < 2; ++rg)
#pragma unroll
    for (int r = 0; r < 4; ++r) {
      const float inv = 1.0f / lrun[rg][r];
      const int qr = qw + rg*16 + lg*4 + r;
      __hip_bfloat16* op = out + (rowbase + qr) * (NHH * DHH) + hh * DHH;
#pragma unroll
      for (int ni = 0; ni < 4; ++ni)
        op[ni*16 + lr] = __float2bfloat16(o[rg][ni][r] * inv);
    }
}

// ---------------- launch ----------------
extern "C" void kernel_launch(void* const* d_in, const int* in_sizes, int n_in,
                              void* d_out, int out_size, void* d_ws, size_t ws_size,
                              hipStream_t stream) {
  (void)in_sizes; (void)n_in; (void)out_size; (void)ws_size;
  const float* x    = (const float*)d_in[0];
  const float* Wa   = (const float*)d_in[1];
  const float* Wout = (const float*)d_in[2];
  const float* bout = (const float*)d_in[3];
  const float* W1   = (const float*)d_in[4];
  const float* b1   = (const float*)d_in[5];
  const float* W2   = (const float*)d_in[6];
  const float* b2   = (const float*)d_in[7];
  const float* g1   = (const float*)d_in[8];
  const float* be1  = (const float*)d_in[9];
  const float* g2   = (const float*)d_in[10];
  const float* be2  = (const float*)d_in[11];

  // workspace layout (80 MB total, lifetime-overlapped):
  char* ws = (char*)d_ws;
  __hip_bfloat16* WaT   = (__hip_bfloat16*)(ws + 0);         // [0,6M)   dead after QKV
  __hip_bfloat16* WoutT = (__hip_bfloat16*)(ws + 6291456);   // [6,8M)   dead after Wout
  __hip_bfloat16* W1T   = (__hip_bfloat16*)(ws + 8388608);   // [8,16M)  dead after FFN1
  __hip_bfloat16* W2T   = (__hip_bfloat16*)(ws + 16777216);  // [16,24M) live to FFN2
  __hip_bfloat16* o1    = (__hip_bfloat16*)(ws + 25165824);  // [24,32M) dead after QKV
  __hip_bfloat16* qkv   = (__hip_bfloat16*)(ws + 33554432);  // [32,56M) dead after attn
  __hip_bfloat16* VT    = (__hip_bfloat16*)(ws + 58720256);  // [56,64M) dead after attn
  __hip_bfloat16* attnb = (__hip_bfloat16*)(ws + 67108864);  // [64,72M) dead after Wout
  float*          ybuf  = (float*)(ws + 33554432);           // [32,48M) alias qkv
  __hip_bfloat16* ln2b  = (__hip_bfloat16*)(ws + 25165824);  // alias o1
  __hip_bfloat16* hbuf  = (__hip_bfloat16*)(ws + 50331648);  // [48,80M)
  float*          P0    = (float*)(ws + 0);                  // [0,16M)  alias weights
  float*          P1    = (float*)(ws + 33554432);           // [32,48M) alias ybuf

  convT_kernel<<<dim3(NQKV/32, EE/32), 256, 0, stream>>>(Wa, WaT, EE, NQKV);
  convT_kernel<<<dim3(EE/32, EE/32), 256, 0, stream>>>(Wout, WoutT, EE, EE);
  convT_kernel<<<dim3(HIDD/32, EE/32), 256, 0, stream>>>(W1, W1T, EE, HIDD);
  convT_kernel<<<dim3(EE/32, HIDD/32), 256, 0, stream>>>(W2, W2T, HIDD, EE);
  ln_kernel<<<MTOK, 256, 0, stream>>>(x, g1, be1, o1);
  gemm_qkv<<<dim3(NQKV/128, MTOK/128), 256, 0, stream>>>(o1, WaT, qkv);
  vtrans_kernel<<<dim3(LL/32, DHH/32, BB*NHH), 256, 0, stream>>>(qkv, VT);
  attn_kernel<<<dim3(LL/128, NHH, BB), 256, 0, stream>>>(qkv, VT, attnb);
  gemm_wout<<<dim3(EE/128, MTOK/128), 256, 0, stream>>>(attnb, WoutT, ybuf, bout, x);
  ln_kernel<<<MTOK, 256, 0, stream>>>(ybuf, g2, be2, ln2b);
  gemm_ffn1<<<dim3(HIDD/128, MTOK/128), 256, 0, stream>>>(ln2b, W1T, hbuf, b1);
  gemm_ffn2p<<<dim3(EE/64, MTOK/128, 2), 256, 0, stream>>>(hbuf, W2T, P0, P1);
  ffn2_reduce<<<2048, 256, 0, stream>>>((const float4*)P0, (const float4*)P1,
                                        (const float4*)x, b2, (float4*)d_out);
}